// Round 10
// baseline (246.063 us; speedup 1.0000x reference)
//
#include <hip/hip_runtime.h>
#include <math.h>

// Fixed problem shapes (CausalSelfAttention: B=2, T=2048, C=1024, H=16)
#define B_ 2
#define T_ 2048
#define C_ 1024
#define H_ 16
#define D_ 64
#define M_ (B_*T_)   // 4096 rows

typedef __bf16 bf16x8 __attribute__((ext_vector_type(8)));
typedef __bf16 bf16x4 __attribute__((ext_vector_type(4)));
typedef float  f32x4  __attribute__((ext_vector_type(4)));

__device__ __forceinline__ unsigned short f2bf(float f) {
    unsigned int u = __float_as_uint(f);
    u += 0x7FFFu + ((u >> 16) & 1u);
    return (unsigned short)(u >> 16);
}

// async 16B global->LDS (wave-uniform LDS base + lane*16; global addr per-lane)
__device__ __forceinline__ void gload16(const void* g, void* l) {
    __builtin_amdgcn_global_load_lds(
        (const __attribute__((address_space(1))) void*)g,
        (__attribute__((address_space(3))) void*)l, 16, 0, 0);
}

// ---------------------------------------------------------------------------
// Fused prep: blocks [0,2048) convert query fp32->bf16; blocks [2048,6144)
// transpose+convert the 4 weights; block 6144 zeroes the 256 pair-counters
// (runs 3 dispatches before flash -> ordering by stream serialization).
// ---------------------------------------------------------------------------
__global__ __launch_bounds__(256) void prep_kernel(
    const float* __restrict__ X, unsigned short* __restrict__ Xb,
    const float* __restrict__ W0, const float* __restrict__ W1,
    const float* __restrict__ W2, const float* __restrict__ W3,
    unsigned short* __restrict__ T0, unsigned short* __restrict__ T1,
    unsigned short* __restrict__ T2, unsigned short* __restrict__ T3,
    int* __restrict__ counters)
{
    const int tid = threadIdx.x;
    if (blockIdx.x == 6144) {
        if (tid < 256) counters[tid] = 0;
        return;
    }
    if (blockIdx.x < 2048) {
        const size_t i = ((size_t)blockIdx.x * 256 + tid) * 8;
        const float4 a = *(const float4*)&X[i];
        const float4 b = *(const float4*)&X[i + 4];
        ushort4 s0, s1;
        s0.x = f2bf(a.x); s0.y = f2bf(a.y); s0.z = f2bf(a.z); s0.w = f2bf(a.w);
        s1.x = f2bf(b.x); s1.y = f2bf(b.y); s1.z = f2bf(b.z); s1.w = f2bf(b.w);
        *(ushort4*)&Xb[i]     = s0;
        *(ushort4*)&Xb[i + 4] = s1;
        return;
    }
    const int bz = blockIdx.x - 2048;          // 0..4095
    const int z = bz >> 10, rem = bz & 1023;
    const float* W; unsigned short* Wt;
    switch (z) {
        case 0: W = W0; Wt = T0; break;
        case 1: W = W1; Wt = T1; break;
        case 2: W = W2; Wt = T2; break;
        default: W = W3; Wt = T3; break;
    }
    __shared__ unsigned short tile[32][33];
    const int k0 = (rem >> 5) * 32, n0 = (rem & 31) * 32;
    {
        const int r = tid >> 3, c = (tid & 7) * 4;
        const float4 v = *(const float4*)&W[(size_t)(k0 + r)*C_ + n0 + c];
        tile[c+0][r] = f2bf(v.x);
        tile[c+1][r] = f2bf(v.y);
        tile[c+2][r] = f2bf(v.z);
        tile[c+3][r] = f2bf(v.w);
    }
    __syncthreads();
    {
        const int r = tid >> 3, c = (tid & 7) * 4;
        ushort4 s;
        s.x = tile[r][c+0]; s.y = tile[r][c+1]; s.z = tile[r][c+2]; s.w = tile[r][c+3];
        *(ushort4*)&Wt[(size_t)(n0 + r)*C_ + k0 + c] = s;
    }
}

// ---------------------------------------------------------------------------
// bf16 MFMA GEMM (m97 structure, BK=64) — unchanged from round 9.
// ---------------------------------------------------------------------------
__global__ __launch_bounds__(256) void gemm_mfma_kernel(
    const unsigned short* __restrict__ A, const unsigned short* __restrict__ Bt,
    const float* __restrict__ b0, const float* __restrict__ b1,
    const float* __restrict__ b2,
    void* __restrict__ out0, void* __restrict__ out1, void* __restrict__ out2,
    int mode)
{
    __shared__ __align__(16) unsigned short Als[2][128 * 32];
    __shared__ __align__(16) unsigned short Bls[2][128 * 32];

    const int tid  = threadIdx.x;
    const int lane = tid & 63;
    const int wave = tid >> 6;
    const int wm = wave >> 1, wn = wave & 1;
    const int l15 = lane & 15, quad = lane >> 4;
    const int m0 = blockIdx.y * 128, n0 = blockIdx.x * 128;
    const int srow = lane >> 2;
    const int scol = (lane & 3) * 8;

    const f32x4 zero4 = {0.f, 0.f, 0.f, 0.f};
    f32x4 acc[4][4];
    #pragma unroll
    for (int i = 0; i < 4; ++i)
        #pragma unroll
        for (int j = 0; j < 4; ++j) acc[i][j] = zero4;

    for (int k0 = 0; k0 < C_; k0 += 64) {
        __syncthreads();
        #pragma unroll
        for (int h = 0; h < 2; ++h) {
            #pragma unroll
            for (int u = 0; u < 2; ++u) {
                const int r = wave*32 + u*16 + srow;
                gload16(&A [(size_t)(m0 + r)*C_ + k0 + h*32 + scol],
                        &Als[h][(wave*32 + u*16)*32]);
                gload16(&Bt[(size_t)(n0 + r)*C_ + k0 + h*32 + scol],
                        &Bls[h][(wave*32 + u*16)*32]);
            }
        }
        __syncthreads();

        #pragma unroll
        for (int h = 0; h < 2; ++h) {
            bf16x8 af[4], bfr[4];
            #pragma unroll
            for (int i = 0; i < 4; ++i)
                af[i] = *(const bf16x8*)&Als[h][(wm*64 + i*16 + l15)*32 + quad*8];
            #pragma unroll
            for (int j = 0; j < 4; ++j)
                bfr[j] = *(const bf16x8*)&Bls[h][(wn*64 + j*16 + l15)*32 + quad*8];

            #pragma unroll
            for (int i = 0; i < 4; ++i)
                #pragma unroll
                for (int j = 0; j < 4; ++j)
                    acc[i][j] = __builtin_amdgcn_mfma_f32_16x16x32_bf16(
                        af[i], bfr[j], acc[i][j], 0, 0, 0);
        }
    }

    if (mode == 0) {
        float* o0 = (float*)out0;
        #pragma unroll
        for (int j = 0; j < 4; ++j) {
            const int n = n0 + wn*64 + j*16 + l15;
            const float bias = b0[n];
            #pragma unroll
            for (int i = 0; i < 4; ++i)
                #pragma unroll
                for (int r = 0; r < 4; ++r) {
                    const int m = m0 + wm*64 + i*16 + quad*4 + r;
                    o0[(size_t)m*C_ + n] = acc[i][j][r] + bias;
                }
        }
        return;
    }

    // ---- mode 1: LDS-assisted QKV epilogue ----
    __syncthreads();
    unsigned short* Ep = (wave < 2) ? &Als[wave][0] : &Bls[wave - 2][0];  // 8 KB

    const int which = n0 >> 10;
    const int c0 = n0 & (C_ - 1);
    const int h  = (c0 >> 6) + wn;
    const int bb = m0 >> 11;
    const int t0 = (m0 & (T_ - 1)) + wm*64;
    const int bh = bb*H_ + h;
    const float* bp = (which == 0) ? b0 : (which == 1 ? b1 : b2);
    const float qscale = (which == 0) ? 0.125f : 1.0f;

    if (which < 2) {
        #pragma unroll
        for (int j = 0; j < 4; ++j) {
            const int cl = j*16 + l15;
            const float bias = bp[c0 + wn*64 + cl];
            #pragma unroll
            for (int i = 0; i < 4; ++i)
                #pragma unroll
                for (int r = 0; r < 4; ++r)
                    Ep[(i*16 + quad*4 + r)*64 + cl] =
                        f2bf((acc[i][j][r] + bias) * qscale);
        }
        unsigned short* op = (which == 0) ? (unsigned short*)out0
                                          : (unsigned short*)out1;
        const int chunk = lane & 7;
        #pragma unroll
        for (int u = 0; u < 8; ++u) {
            const int row = u*8 + (lane >> 3);
            const uint4 v = *(const uint4*)&Ep[row*64 + chunk*8];
            *(uint4*)&op[((size_t)bh*T_ + t0 + row)*D_ + chunk*8] = v;
        }
    } else {
        #pragma unroll
        for (int j = 0; j < 4; ++j) {
            const int cl = j*16 + l15;
            const float bias = bp[c0 + wn*64 + cl];
            const int xo = (l15 & 7) * 8;
            #pragma unroll
            for (int i = 0; i < 4; ++i) {
                ushort4 pk;
                pk.x = f2bf(acc[i][j][0] + bias);
                pk.y = f2bf(acc[i][j][1] + bias);
                pk.z = f2bf(acc[i][j][2] + bias);
                pk.w = f2bf(acc[i][j][3] + bias);
                *(ushort4*)&Ep[cl*64 + ((i*16 + quad*4) ^ xo)] = pk;
            }
        }
        unsigned short* op = (unsigned short*)out2;
        const int chunk = lane & 7;
        #pragma unroll
        for (int u = 0; u < 8; ++u) {
            const int d = u*8 + (lane >> 3);
            const uint4 v = *(const uint4*)&Ep[d*64 + ((chunk*8) ^ ((d & 7)*8))];
            *(uint4*)&op[((size_t)bh*D_ + d)*T_ + t0 + chunk*8] = v;
        }
    }
}

// ---------------------------------------------------------------------------
// MFMA flash attention v4: pair-balanced causal scheduling (round 9) +
// double KV staging (2 tiles per barrier pair) + FUSED merge:
// each pair's two producers atomicAdd a counter after a device fence; the
// second arrival acquires and merges that pair inline (last-producer-merges).
// Removes the merge dispatch; merge overlaps the flash tail.
// ---------------------------------------------------------------------------
__global__ __launch_bounds__(256) void flash_mfma_kernel(
    const unsigned short* __restrict__ Qs, const unsigned short* __restrict__ Ks,
    const unsigned short* __restrict__ Vts, unsigned short* __restrict__ Y,
    float* __restrict__ parts, float* __restrict__ lbase,
    int* __restrict__ counters)
{
    __shared__ __align__(16) unsigned short Kls[2][64 * 64];   // 16 KB
    __shared__ __align__(16) unsigned short Vls[2][64 * 64];   // 16 KB
    __shared__ __align__(16) unsigned short Pls[4 * 2048];     // 16 KB
    __shared__ int doMerge;

    const int tid  = threadIdx.x;
    const int lane = tid & 63, wave = tid >> 6;
    const int l15  = lane & 15, quad = lane >> 4;
    const int job  = blockIdx.x >> 5;    // 0..15
    const int bh   = blockIdx.x & 31;
    const bool isA = (job < 8);
    const int a    = isA ? job : job - 8;

    int qts[2], slos[2], shis[2], slots[2], nseg;
    if (isA) {
        qts[0] = a;      slos[0] = 0;        shis[0] = 2*a + 2;  slots[0] = -1;
        qts[1] = 15 - a; slos[1] = 0;        shis[1] = 15 - 2*a; slots[1] = 0;
        nseg = 2;
    } else {
        qts[0] = 15 - a; slos[0] = 15 - 2*a; shis[0] = 32 - 2*a; slots[0] = 1;
        nseg = 1;
    }

    unsigned short* Pw = &Pls[wave * 2048];
    const int kd_s = wave >> 1;
    const int c8_s = (kd_s * 4 + quad) * 8;
    const int b_ = bh >> 4, h_ = bh & (H_ - 1);
    const f32x4 zero4 = {0.f, 0.f, 0.f, 0.f};
    bool wrotePartial = false;

    for (int sg = 0; sg < nseg; ++sg) {
        const int qt  = qts[sg];
        const int qw0 = qt * 128 + wave * 32;

        bf16x8 qf[2][2];
        #pragma unroll
        for (int i = 0; i < 2; ++i)
            #pragma unroll
            for (int kd = 0; kd < 2; ++kd)
                qf[i][kd] = *(const bf16x8*)&Qs[((size_t)bh*T_ + qw0 + i*16 + l15)*D_
                                                + kd*32 + quad*8];

        f32x4 o[2][4];
        #pragma unroll
        for (int i = 0; i < 2; ++i)
            #pragma unroll
            for (int jd = 0; jd < 4; ++jd) o[i][jd] = zero4;
        float lsum[2] = {0.f, 0.f};

        for (int it = slos[sg]; it < shis[sg]; it += 2) {
            const bool two = (it + 1 < shis[sg]);
            __syncthreads();
            #pragma unroll
            for (int u = 0; u < 2; ++u) {
                const int cu  = 2*wave + u;
                const int row = ((cu & 3) << 4) + l15;
                gload16(&Ks [((size_t)bh*T_ + it*64 + row)*D_ + c8_s],
                        (char*)&Kls[0][0] + cu*1024);
                gload16(&Vts[((size_t)bh*D_ + row)*T_ + it*64 + c8_s],
                        (char*)&Vls[0][0] + cu*1024);
            }
            if (two) {
                #pragma unroll
                for (int u = 0; u < 2; ++u) {
                    const int cu  = 2*wave + u;
                    const int row = ((cu & 3) << 4) + l15;
                    gload16(&Ks [((size_t)bh*T_ + (it+1)*64 + row)*D_ + c8_s],
                            (char*)&Kls[1][0] + cu*1024);
                    gload16(&Vts[((size_t)bh*D_ + row)*T_ + (it+1)*64 + c8_s],
                            (char*)&Vls[1][0] + cu*1024);
                }
            }
            __syncthreads();

            #pragma unroll
            for (int tt = 0; tt < 2; ++tt) {
                if (tt && !two) break;
                const int s0 = (it + tt) * 64;
                if (s0 > qw0 + 31) continue;   // no barriers inside -> safe

                // ---- S^T = K·Q^T ----
                f32x4 st[2][4];
                #pragma unroll
                for (int i = 0; i < 2; ++i)
                    #pragma unroll
                    for (int j = 0; j < 4; ++j) st[i][j] = zero4;
                #pragma unroll
                for (int kd = 0; kd < 2; ++kd) {
                    bf16x8 kf[4];
                    #pragma unroll
                    for (int j = 0; j < 4; ++j)
                        kf[j] = *(const bf16x8*)&Kls[tt][lane*8 + j*512 + kd*2048];
                    #pragma unroll
                    for (int i = 0; i < 2; ++i)
                        #pragma unroll
                        for (int j = 0; j < 4; ++j)
                            st[i][j] = __builtin_amdgcn_mfma_f32_16x16x32_bf16(
                                kf[j], qf[i][kd], st[i][j], 0, 0, 0);
                }

                // ---- p = exp(s) (+ causal mask on diag tiles), row-sum ----
                const bool diag = (s0 + 63 > qw0);
                #pragma unroll
                for (int i = 0; i < 2; ++i) {
                    const int qrow = qw0 + i*16 + l15;
                    #pragma unroll
                    for (int j = 0; j < 4; ++j)
                        #pragma unroll
                        for (int r = 0; r < 4; ++r) {
                            float e = __expf(st[i][j][r]);
                            if (diag && (s0 + j*16 + quad*4 + r > qrow)) e = 0.f;
                            st[i][j][r] = e;
                            lsum[i] += e;
                        }
                }

                // ---- P -> LDS (8 x b64, bijective layout) ----
                #pragma unroll
                for (int i = 0; i < 2; ++i)
                    #pragma unroll
                    for (int j = 0; j < 4; ++j) {
                        bf16x4 pk = {(__bf16)st[i][j][0], (__bf16)st[i][j][1],
                                     (__bf16)st[i][j][2], (__bf16)st[i][j][3]};
                        *(bf16x4*)&Pw[(((j>>1)*2 + i)*4 + (j&1)*2 + (quad>>1))*128
                                       + l15*8 + (quad&1)*4] = pk;
                    }

                // ---- O^T += V^T·P ----
                #pragma unroll
                for (int kk = 0; kk < 2; ++kk) {
                    bf16x8 pf[2], vf[4];
                    #pragma unroll
                    for (int i = 0; i < 2; ++i)
                        pf[i] = *(const bf16x8*)&Pw[(kk*2 + i)*512 + lane*8];
                    #pragma unroll
                    for (int jd = 0; jd < 4; ++jd)
                        vf[jd] = *(const bf16x8*)&Vls[tt][lane*8 + jd*512 + kk*2048];
                    #pragma unroll
                    for (int i = 0; i < 2; ++i)
                        #pragma unroll
                        for (int jd = 0; jd < 4; ++jd)
                            o[i][jd] = __builtin_amdgcn_mfma_f32_16x16x32_bf16(
                                vf[jd], pf[i], o[i][jd], 0, 0, 0);
                }
            }
        }

        // ---- reduce row-sums across quads ----
        #pragma unroll
        for (int i = 0; i < 2; ++i) {
            float v = lsum[i];
            v += __shfl_xor(v, 16, 64);
            v += __shfl_xor(v, 32, 64);
            lsum[i] = v;
        }

        if (slots[sg] < 0) {
            // direct write Y bf16
            #pragma unroll
            for (int i = 0; i < 2; ++i) {
                const float inv = 1.0f / lsum[i];
                const int t = qts[sg]*128 + wave*32 + i*16 + l15;
                #pragma unroll
                for (int jd = 0; jd < 4; ++jd) {
                    bf16x4 pk = {(__bf16)(o[i][jd][0] * inv),
                                 (__bf16)(o[i][jd][1] * inv),
                                 (__bf16)(o[i][jd][2] * inv),
                                 (__bf16)(o[i][jd][3] * inv)};
                    *(bf16x4*)&Y[((size_t)(b_*T_ + t))*C_ + h_*D_ + jd*16 + quad*4]
                        = pk;
                }
            }
        } else {
            // partial: fp32 O [128][64] + l [128] into slot
            const int gpi = bh*16 + a*2 + slots[sg];
            float* Op = parts + (size_t)gpi*8192;
            float* Lp = lbase + gpi*128;
            #pragma unroll
            for (int i = 0; i < 2; ++i) {
                const int tl = wave*32 + i*16 + l15;
                if (quad == 0) Lp[tl] = lsum[i];
                #pragma unroll
                for (int jd = 0; jd < 4; ++jd)
                    *(f32x4*)&Op[(size_t)tl*64 + jd*16 + quad*4] = o[i][jd];
            }
            wrotePartial = true;
        }
    }

    // ---- fused merge: last producer of the pair merges it ----
    if (wrotePartial) {
        __syncthreads();                       // all partial stores issued
        if (tid == 0) {
            __threadfence();                   // release partials device-wide
            const int old = atomicAdd(&counters[bh*8 + a], 1);
            doMerge = (old == 1);
        }
        __syncthreads();
        if (doMerge) {
            __threadfence();                   // acquire other producer's data
            const int qt = 15 - a;
            const int g0 = bh*16 + a*2;
            const float* O0 = parts + (size_t)g0*8192;
            const float* O1 = O0 + 8192;
            const float* L0 = lbase + g0*128;
            const float* L1 = L0 + 128;
            const int r = tid >> 1, c0m = (tid & 1) * 32;
            const float inv = 1.0f / (L0[r] + L1[r]);
            const int t = qt*128 + r;
            #pragma unroll
            for (int k = 0; k < 8; ++k) {
                const f32x4 x0 = *(const f32x4*)&O0[(size_t)r*64 + c0m + k*4];
                const f32x4 x1 = *(const f32x4*)&O1[(size_t)r*64 + c0m + k*4];
                bf16x4 pk = {(__bf16)((x0[0]+x1[0])*inv),
                             (__bf16)((x0[1]+x1[1])*inv),
                             (__bf16)((x0[2]+x1[2])*inv),
                             (__bf16)((x0[3]+x1[3])*inv)};
                *(bf16x4*)&Y[((size_t)(b_*T_ + t))*C_ + h_*D_ + c0m + k*4] = pk;
            }
        }
    }
}

// ---------------------------------------------------------------------------
extern "C" void kernel_launch(void* const* d_in, const int* in_sizes, int n_in,
                              void* d_out, int out_size, void* d_ws, size_t ws_size,
                              hipStream_t stream) {
    const float* query = (const float*)d_in[0];
    const float* Wq = (const float*)d_in[1];
    const float* bq = (const float*)d_in[2];
    const float* Wk = (const float*)d_in[3];
    const float* bk = (const float*)d_in[4];
    const float* Wv = (const float*)d_in[5];
    const float* bv = (const float*)d_in[6];
    const float* Wp = (const float*)d_in[7];
    const float* bp = (const float*)d_in[8];
    float* out = (float*)d_out;

    // Workspace layout (bytes):
    //   [0,       8.39M)  q bf16 [bh][t][d], pre-scaled by 0.125
    //   [8.39M,  16.78M)  k bf16 [bh][t][d]
    //   [16.78M, 25.17M)  v bf16 [bh][d][t] (transposed)
    //   [25.17M, 27.26M)  WtP   bf16 (Wp^T)
    //   [27.26M, 33.55M)  WtQKV bf16; dead after QKV GEMM -> lbase (512x128 f32)
    //   [33.55M, 41.94M)  yb    bf16 [B*T][C] (attention output)
    //   [41.94M, 50.33M)  qx    bf16 query (dead after QKV GEMM)
    //   [50.33M, +1KB  )  pair counters (zeroed by prep block 6144)
    // Flash fp32 O-partials (512 x 32KB = 16.78MB) live in d_out (dead until
    // the proj GEMM overwrites it).
    char* ws = (char*)d_ws;
    unsigned short* qbf   = (unsigned short*)(ws);
    unsigned short* kbf   = (unsigned short*)(ws + 8388608);
    unsigned short* vtbf  = (unsigned short*)(ws + 16777216);
    unsigned short* WtP   = (unsigned short*)(ws + 25165824);
    unsigned short* WtQKV = (unsigned short*)(ws + 27262976);
    unsigned short* yb    = (unsigned short*)(ws + 33554432);
    unsigned short* qx    = (unsigned short*)(ws + 41943040);
    float* lbase    = (float*)(ws + 27262976);          // 512 x 128 floats
    int*   counters = (int*)  (ws + 50331648);          // 256 ints
    float* parts    = out;                              // 512 x 8192 floats

    prep_kernel<<<6145, 256, 0, stream>>>(
        query, qx, Wq, Wk, Wv, Wp,
        WtQKV, WtQKV + (size_t)C_*C_, WtQKV + 2*(size_t)C_*C_, WtP, counters);

    // Fused QKV GEMM: M=4096, N=3072
    gemm_mfma_kernel<<<dim3(3*C_/128, M_/128), 256, 0, stream>>>(
        qx, WtQKV, bq, bk, bv, qbf, kbf, vtbf, 1);

    flash_mfma_kernel<<<512, 256, 0, stream>>>(qbf, kbf, vtbf, yb,
                                               parts, lbase, counters);

    // Output projection: M=4096, N=1024 (fp32 out) — overwrites the partials
    gemm_mfma_kernel<<<dim3(C_/128, M_/128), 256, 0, stream>>>(
        yb, WtP, bp, bp, bp, out, nullptr, nullptr, 0);
}

// Round 12
// 209.436 us; speedup vs baseline: 1.1749x; 1.1749x over previous
//
#include <hip/hip_runtime.h>
#include <math.h>

// Fixed problem shapes (CausalSelfAttention: B=2, T=2048, C=1024, H=16)
#define B_ 2
#define T_ 2048
#define C_ 1024
#define H_ 16
#define D_ 64
#define M_ (B_*T_)   // 4096 rows

typedef __bf16 bf16x8 __attribute__((ext_vector_type(8)));
typedef __bf16 bf16x4 __attribute__((ext_vector_type(4)));
typedef float  f32x4  __attribute__((ext_vector_type(4)));

__device__ __forceinline__ unsigned short f2bf(float f) {
    unsigned int u = __float_as_uint(f);
    u += 0x7FFFu + ((u >> 16) & 1u);
    return (unsigned short)(u >> 16);
}

// async 16B global->LDS (wave-uniform LDS base + lane*16; global addr per-lane)
__device__ __forceinline__ void gload16(const void* g, void* l) {
    __builtin_amdgcn_global_load_lds(
        (const __attribute__((address_space(1))) void*)g,
        (__attribute__((address_space(3))) void*)l, 16, 0, 0);
}

// ---------------------------------------------------------------------------
// Fused prep: blocks [0,2048) convert query fp32->bf16 (8 elems/thread);
// blocks [2048,6144) transpose+convert the 4 weights (32x32 tiles).
// ---------------------------------------------------------------------------
__global__ __launch_bounds__(256) void prep_kernel(
    const float* __restrict__ X, unsigned short* __restrict__ Xb,
    const float* __restrict__ W0, const float* __restrict__ W1,
    const float* __restrict__ W2, const float* __restrict__ W3,
    unsigned short* __restrict__ T0, unsigned short* __restrict__ T1,
    unsigned short* __restrict__ T2, unsigned short* __restrict__ T3)
{
    const int tid = threadIdx.x;
    if (blockIdx.x < 2048) {
        const size_t i = ((size_t)blockIdx.x * 256 + tid) * 8;
        const float4 a = *(const float4*)&X[i];
        const float4 b = *(const float4*)&X[i + 4];
        ushort4 s0, s1;
        s0.x = f2bf(a.x); s0.y = f2bf(a.y); s0.z = f2bf(a.z); s0.w = f2bf(a.w);
        s1.x = f2bf(b.x); s1.y = f2bf(b.y); s1.z = f2bf(b.z); s1.w = f2bf(b.w);
        *(ushort4*)&Xb[i]     = s0;
        *(ushort4*)&Xb[i + 4] = s1;
        return;
    }
    const int bz = blockIdx.x - 2048;          // 0..4095
    const int z = bz >> 10, rem = bz & 1023;
    const float* W; unsigned short* Wt;
    switch (z) {
        case 0: W = W0; Wt = T0; break;
        case 1: W = W1; Wt = T1; break;
        case 2: W = W2; Wt = T2; break;
        default: W = W3; Wt = T3; break;
    }
    __shared__ unsigned short tile[32][33];
    const int k0 = (rem >> 5) * 32, n0 = (rem & 31) * 32;
    {
        const int r = tid >> 3, c = (tid & 7) * 4;
        const float4 v = *(const float4*)&W[(size_t)(k0 + r)*C_ + n0 + c];
        tile[c+0][r] = f2bf(v.x);
        tile[c+1][r] = f2bf(v.y);
        tile[c+2][r] = f2bf(v.z);
        tile[c+3][r] = f2bf(v.w);
    }
    __syncthreads();
    {
        const int r = tid >> 3, c = (tid & 7) * 4;
        ushort4 s;
        s.x = tile[r][c+0]; s.y = tile[r][c+1]; s.z = tile[r][c+2]; s.w = tile[r][c+3];
        *(ushort4*)&Wt[(size_t)(n0 + r)*C_ + k0 + c] = s;
    }
}

// ---------------------------------------------------------------------------
// bf16 MFMA GEMM (m97 structure, BK=64): out = A[M_,1024]bf16 @ Wt^T + bias.
// mode 0: fp32 out via LDS-assisted coalesced epilogue (2 passes/wave,
//         2-way-swizzled banks = free; 16 coalesced 16B stores per thread
//         instead of 64 scattered 4B dword stores).
// mode 1: QKV epilogue (round-8 LDS-assisted structure); q pre-scaled by
//         0.125/ln2 so flash can use exp2 (v_exp_f32 IS 2^x).
// ---------------------------------------------------------------------------
__global__ __launch_bounds__(256) void gemm_mfma_kernel(
    const unsigned short* __restrict__ A, const unsigned short* __restrict__ Bt,
    const float* __restrict__ b0, const float* __restrict__ b1,
    const float* __restrict__ b2,
    void* __restrict__ out0, void* __restrict__ out1, void* __restrict__ out2,
    int mode)
{
    __shared__ __align__(16) unsigned short Als[2][128 * 32];
    __shared__ __align__(16) unsigned short Bls[2][128 * 32];

    const int tid  = threadIdx.x;
    const int lane = tid & 63;
    const int wave = tid >> 6;
    const int wm = wave >> 1, wn = wave & 1;
    const int l15 = lane & 15, quad = lane >> 4;
    const int m0 = blockIdx.y * 128, n0 = blockIdx.x * 128;
    const int srow = lane >> 2;
    const int scol = (lane & 3) * 8;

    const f32x4 zero4 = {0.f, 0.f, 0.f, 0.f};
    f32x4 acc[4][4];
    #pragma unroll
    for (int i = 0; i < 4; ++i)
        #pragma unroll
        for (int j = 0; j < 4; ++j) acc[i][j] = zero4;

    for (int k0 = 0; k0 < C_; k0 += 64) {
        __syncthreads();
        #pragma unroll
        for (int h = 0; h < 2; ++h) {
            #pragma unroll
            for (int u = 0; u < 2; ++u) {
                const int r = wave*32 + u*16 + srow;
                gload16(&A [(size_t)(m0 + r)*C_ + k0 + h*32 + scol],
                        &Als[h][(wave*32 + u*16)*32]);
                gload16(&Bt[(size_t)(n0 + r)*C_ + k0 + h*32 + scol],
                        &Bls[h][(wave*32 + u*16)*32]);
            }
        }
        __syncthreads();

        #pragma unroll
        for (int h = 0; h < 2; ++h) {
            bf16x8 af[4], bfr[4];
            #pragma unroll
            for (int i = 0; i < 4; ++i)
                af[i] = *(const bf16x8*)&Als[h][(wm*64 + i*16 + l15)*32 + quad*8];
            #pragma unroll
            for (int j = 0; j < 4; ++j)
                bfr[j] = *(const bf16x8*)&Bls[h][(wn*64 + j*16 + l15)*32 + quad*8];

            #pragma unroll
            for (int i = 0; i < 4; ++i)
                #pragma unroll
                for (int j = 0; j < 4; ++j)
                    acc[i][j] = __builtin_amdgcn_mfma_f32_16x16x32_bf16(
                        af[i], bfr[j], acc[i][j], 0, 0, 0);
        }
    }

    __syncthreads();   // retire last-iter fragment reads before LDS re-use
    const int nb = n0 + wn*64;
    const int mb = m0 + wm*64;

    if (mode == 0) {
        // ---- mode 0: LDS-assisted fp32 epilogue (wave-private 8KB slice) ----
        float* Epf = (float*)((wave < 2) ? &Als[wave][0] : &Bls[wave - 2][0]);
        float* o0 = (float*)out0;
        float bias[4];
        #pragma unroll
        for (int j = 0; j < 4; ++j) bias[j] = b0[nb + j*16 + l15];
        const int cswz = (quad & 1) * 16;          // 2-way bank spread (free)
        #pragma unroll
        for (int p = 0; p < 2; ++p) {
            #pragma unroll
            for (int ii = 0; ii < 2; ++ii) {
                const int i = p*2 + ii;
                #pragma unroll
                for (int j = 0; j < 4; ++j)
                    #pragma unroll
                    for (int r = 0; r < 4; ++r)
                        Epf[(ii*16 + quad*4 + r)*64 + ((j*16 + l15) ^ cswz)] =
                            acc[i][j][r] + bias[j];
            }
            // same-wave DS ordering: reads below see the writes above
            const int xb = (lane >> 5) * 4;        // row-parity chunk swizzle
            #pragma unroll
            for (int u = 0; u < 4; ++u) {
                const int row = u*8 + (lane >> 3);
                #pragma unroll
                for (int cc = 0; cc < 2; ++cc) {
                    const int chunk = (lane & 7) + cc*8;
                    const f32x4 v =
                        *(const f32x4*)&Epf[row*64 + ((chunk ^ xb) * 4)];
                    *(f32x4*)&o0[(size_t)(mb + p*32 + row)*C_ + nb + chunk*4] = v;
                }
            }
            // next pass overwrites same slice; same-wave ordering suffices
        }
        return;
    }

    // ---- mode 1: LDS-assisted QKV epilogue ----
    unsigned short* Ep = (wave < 2) ? &Als[wave][0] : &Bls[wave - 2][0];  // 8 KB

    const int which = n0 >> 10;
    const int c0 = n0 & (C_ - 1);
    const int h  = (c0 >> 6) + wn;
    const int bb = m0 >> 11;
    const int t0 = (m0 & (T_ - 1)) + wm*64;
    const int bh = bb*H_ + h;
    const float* bp = (which == 0) ? b0 : (which == 1 ? b1 : b2);
    // q pre-scale folds softmax scale AND 1/ln2 (flash uses exp2)
    const float qscale = (which == 0) ? 0.125f * 1.44269504089f : 1.0f;

    if (which < 2) {
        #pragma unroll
        for (int j = 0; j < 4; ++j) {
            const int cl = j*16 + l15;
            const float bias = bp[c0 + wn*64 + cl];
            #pragma unroll
            for (int i = 0; i < 4; ++i)
                #pragma unroll
                for (int r = 0; r < 4; ++r)
                    Ep[(i*16 + quad*4 + r)*64 + cl] =
                        f2bf((acc[i][j][r] + bias) * qscale);
        }
        unsigned short* op = (which == 0) ? (unsigned short*)out0
                                          : (unsigned short*)out1;
        const int chunk = lane & 7;
        #pragma unroll
        for (int u = 0; u < 8; ++u) {
            const int row = u*8 + (lane >> 3);
            const uint4 v = *(const uint4*)&Ep[row*64 + chunk*8];
            *(uint4*)&op[((size_t)bh*T_ + t0 + row)*D_ + chunk*8] = v;
        }
    } else {
        #pragma unroll
        for (int j = 0; j < 4; ++j) {
            const int cl = j*16 + l15;
            const float bias = bp[c0 + wn*64 + cl];
            const int xo = (l15 & 7) * 8;
            #pragma unroll
            for (int i = 0; i < 4; ++i) {
                ushort4 pk;
                pk.x = f2bf(acc[i][j][0] + bias);
                pk.y = f2bf(acc[i][j][1] + bias);
                pk.z = f2bf(acc[i][j][2] + bias);
                pk.w = f2bf(acc[i][j][3] + bias);
                *(ushort4*)&Ep[cl*64 + ((i*16 + quad*4) ^ xo)] = pk;
            }
        }
        unsigned short* op = (unsigned short*)out2;
        const int chunk = lane & 7;
        #pragma unroll
        for (int u = 0; u < 8; ++u) {
            const int d = u*8 + (lane >> 3);
            const uint4 v = *(const uint4*)&Ep[d*64 + ((chunk*8) ^ ((d & 7)*8))];
            *(uint4*)&op[((size_t)bh*D_ + d)*T_ + t0 + chunk*8] = v;
        }
    }
}

// ---------------------------------------------------------------------------
// MFMA flash attention v3 (round-9 structure): pair-balanced causal
// scheduling, single KV staging, separate merge kernel, NO device fences.
// p = exp2(s) via __builtin_amdgcn_exp2f — Q pre-scaled by 0.125/ln2 so
// this is exactly e^(s_orig).
// ---------------------------------------------------------------------------
__global__ __launch_bounds__(256) void flash_mfma_kernel(
    const unsigned short* __restrict__ Qs, const unsigned short* __restrict__ Ks,
    const unsigned short* __restrict__ Vts, unsigned short* __restrict__ Y,
    float* __restrict__ parts, float* __restrict__ lbase)
{
    __shared__ __align__(16) unsigned short Kls[64 * 64];   // 8 KB
    __shared__ __align__(16) unsigned short Vls[64 * 64];   // 8 KB
    __shared__ __align__(16) unsigned short Pls[4 * 2048];  // 16 KB (4KB/wave)

    const int tid  = threadIdx.x;
    const int lane = tid & 63, wave = tid >> 6;
    const int l15  = lane & 15, quad = lane >> 4;
    const int job  = blockIdx.x >> 5;    // 0..15
    const int bh   = blockIdx.x & 31;
    const bool isA = (job < 8);
    const int a    = isA ? job : job - 8;

    int qts[2], slos[2], shis[2], slots[2], nseg;
    if (isA) {
        qts[0] = a;      slos[0] = 0;        shis[0] = 2*a + 2;  slots[0] = -1;
        qts[1] = 15 - a; slos[1] = 0;        shis[1] = 15 - 2*a; slots[1] = 0;
        nseg = 2;
    } else {
        qts[0] = 15 - a; slos[0] = 15 - 2*a; shis[0] = 32 - 2*a; slots[0] = 1;
        nseg = 1;
    }

    unsigned short* Pw = &Pls[wave * 2048];
    const int kd_s = wave >> 1;
    const int c8_s = (kd_s * 4 + quad) * 8;
    const int b_ = bh >> 4, h_ = bh & (H_ - 1);
    const f32x4 zero4 = {0.f, 0.f, 0.f, 0.f};

    for (int sg = 0; sg < nseg; ++sg) {
        const int qt  = qts[sg];
        const int qw0 = qt * 128 + wave * 32;

        bf16x8 qf[2][2];
        #pragma unroll
        for (int i = 0; i < 2; ++i)
            #pragma unroll
            for (int kd = 0; kd < 2; ++kd)
                qf[i][kd] = *(const bf16x8*)&Qs[((size_t)bh*T_ + qw0 + i*16 + l15)*D_
                                                + kd*32 + quad*8];

        f32x4 o[2][4];
        #pragma unroll
        for (int i = 0; i < 2; ++i)
            #pragma unroll
            for (int jd = 0; jd < 4; ++jd) o[i][jd] = zero4;
        float lsum[2] = {0.f, 0.f};

        for (int it = slos[sg]; it < shis[sg]; ++it) {
            const int s0 = it * 64;
            __syncthreads();
            #pragma unroll
            for (int u = 0; u < 2; ++u) {
                const int cu  = 2*wave + u;
                const int row = ((cu & 3) << 4) + l15;
                gload16(&Ks [((size_t)bh*T_ + s0 + row)*D_ + c8_s],
                        (char*)Kls + cu*1024);
                gload16(&Vts[((size_t)bh*D_ + row)*T_ + s0 + c8_s],
                        (char*)Vls + cu*1024);
            }
            __syncthreads();

            if (s0 > qw0 + 31) continue;   // wave fully masked (uniform barriers kept)

            // ---- S^T = K·Q^T ----
            f32x4 st[2][4];
            #pragma unroll
            for (int i = 0; i < 2; ++i)
                #pragma unroll
                for (int j = 0; j < 4; ++j) st[i][j] = zero4;
            #pragma unroll
            for (int kd = 0; kd < 2; ++kd) {
                bf16x8 kf[4];
                #pragma unroll
                for (int j = 0; j < 4; ++j)
                    kf[j] = *(const bf16x8*)&Kls[lane*8 + j*512 + kd*2048];
                #pragma unroll
                for (int i = 0; i < 2; ++i)
                    #pragma unroll
                    for (int j = 0; j < 4; ++j)
                        st[i][j] = __builtin_amdgcn_mfma_f32_16x16x32_bf16(
                            kf[j], qf[i][kd], st[i][j], 0, 0, 0);
            }

            // ---- p = exp2(s) (+ causal mask on diag tiles), row-sum ----
            const bool diag = (s0 + 63 > qw0);
            #pragma unroll
            for (int i = 0; i < 2; ++i) {
                const int qrow = qw0 + i*16 + l15;
                #pragma unroll
                for (int j = 0; j < 4; ++j)
                    #pragma unroll
                    for (int r = 0; r < 4; ++r) {
                        float e = __builtin_amdgcn_exp2f(st[i][j][r]);
                        if (diag && (s0 + j*16 + quad*4 + r > qrow)) e = 0.f;
                        st[i][j][r] = e;
                        lsum[i] += e;
                    }
            }

            // ---- P -> LDS (8 x b64, bijective layout) ----
            #pragma unroll
            for (int i = 0; i < 2; ++i)
                #pragma unroll
                for (int j = 0; j < 4; ++j) {
                    bf16x4 pk = {(__bf16)st[i][j][0], (__bf16)st[i][j][1],
                                 (__bf16)st[i][j][2], (__bf16)st[i][j][3]};
                    *(bf16x4*)&Pw[(((j>>1)*2 + i)*4 + (j&1)*2 + (quad>>1))*128
                                   + l15*8 + (quad&1)*4] = pk;
                }

            // ---- O^T += V^T·P ----
            #pragma unroll
            for (int kk = 0; kk < 2; ++kk) {
                bf16x8 pf[2], vf[4];
                #pragma unroll
                for (int i = 0; i < 2; ++i)
                    pf[i] = *(const bf16x8*)&Pw[(kk*2 + i)*512 + lane*8];
                #pragma unroll
                for (int jd = 0; jd < 4; ++jd)
                    vf[jd] = *(const bf16x8*)&Vls[lane*8 + jd*512 + kk*2048];
                #pragma unroll
                for (int i = 0; i < 2; ++i)
                    #pragma unroll
                    for (int jd = 0; jd < 4; ++jd)
                        o[i][jd] = __builtin_amdgcn_mfma_f32_16x16x32_bf16(
                            vf[jd], pf[i], o[i][jd], 0, 0, 0);
            }
        }

        // ---- reduce row-sums across quads ----
        #pragma unroll
        for (int i = 0; i < 2; ++i) {
            float v = lsum[i];
            v += __shfl_xor(v, 16, 64);
            v += __shfl_xor(v, 32, 64);
            lsum[i] = v;
        }

        if (slots[sg] < 0) {
            #pragma unroll
            for (int i = 0; i < 2; ++i) {
                const float inv = 1.0f / lsum[i];
                const int t = qw0 + i*16 + l15;
                #pragma unroll
                for (int jd = 0; jd < 4; ++jd) {
                    bf16x4 pk = {(__bf16)(o[i][jd][0] * inv),
                                 (__bf16)(o[i][jd][1] * inv),
                                 (__bf16)(o[i][jd][2] * inv),
                                 (__bf16)(o[i][jd][3] * inv)};
                    *(bf16x4*)&Y[((size_t)(b_*T_ + t))*C_ + h_*D_ + jd*16 + quad*4]
                        = pk;
                }
            }
        } else {
            const int gpi = bh*16 + a*2 + slots[sg];
            float* Op = parts + (size_t)gpi*8192;
            float* Lp = lbase + gpi*128;
            #pragma unroll
            for (int i = 0; i < 2; ++i) {
                const int tl = wave*32 + i*16 + l15;
                if (quad == 0) Lp[tl] = lsum[i];
                #pragma unroll
                for (int jd = 0; jd < 4; ++jd)
                    *(f32x4*)&Op[(size_t)tl*64 + jd*16 + quad*4] = o[i][jd];
            }
        }
    }
}

// ---------------------------------------------------------------------------
// Merge split partials: Y = (O0+O1)/(l0+l1), bf16. Grid 256 (32 bh x 8 pairs).
// ---------------------------------------------------------------------------
__global__ __launch_bounds__(256) void merge_kernel(
    const float* __restrict__ parts, const float* __restrict__ lbase,
    unsigned short* __restrict__ Y)
{
    const int pair = blockIdx.x;          // 0..255
    const int bh = pair >> 3, p = pair & 7;
    const int qt = 15 - p;
    const int g0 = bh*16 + p*2;
    const float* O0 = parts + (size_t)g0*8192;
    const float* O1 = O0 + 8192;
    const float* L0 = lbase + g0*128;
    const float* L1 = L0 + 128;

    const int tid = threadIdx.x;
    const int r = tid >> 1, c0 = (tid & 1) * 32;
    const float inv = 1.0f / (L0[r] + L1[r]);
    const int b = bh >> 4, h = bh & (H_ - 1);
    const int t = qt*128 + r;
    #pragma unroll
    for (int k = 0; k < 8; ++k) {
        const f32x4 a  = *(const f32x4*)&O0[(size_t)r*64 + c0 + k*4];
        const f32x4 bb = *(const f32x4*)&O1[(size_t)r*64 + c0 + k*4];
        bf16x4 pk = {(__bf16)((a[0]+bb[0])*inv), (__bf16)((a[1]+bb[1])*inv),
                     (__bf16)((a[2]+bb[2])*inv), (__bf16)((a[3]+bb[3])*inv)};
        *(bf16x4*)&Y[((size_t)(b*T_ + t))*C_ + h*D_ + c0 + k*4] = pk;
    }
}

// ---------------------------------------------------------------------------
extern "C" void kernel_launch(void* const* d_in, const int* in_sizes, int n_in,
                              void* d_out, int out_size, void* d_ws, size_t ws_size,
                              hipStream_t stream) {
    const float* query = (const float*)d_in[0];
    const float* Wq = (const float*)d_in[1];
    const float* bq = (const float*)d_in[2];
    const float* Wk = (const float*)d_in[3];
    const float* bk = (const float*)d_in[4];
    const float* Wv = (const float*)d_in[5];
    const float* bv = (const float*)d_in[6];
    const float* Wp = (const float*)d_in[7];
    const float* bp = (const float*)d_in[8];
    float* out = (float*)d_out;

    // Workspace layout (bytes), total 50.33 MB:
    //   [0,       8.39M)  q bf16 [bh][t][d], pre-scaled by 0.125/ln2
    //   [8.39M,  16.78M)  k bf16 [bh][t][d]
    //   [16.78M, 25.17M)  v bf16 [bh][d][t] (transposed)
    //   [25.17M, 27.26M)  WtP   bf16 (Wp^T)
    //   [27.26M, 33.55M)  WtQKV bf16; dead after QKV GEMM -> lbase (512x128 f32)
    //   [33.55M, 41.94M)  yb    bf16 [B*T][C] (attention output)
    //   [41.94M, 50.33M)  qx    bf16 query (dead after QKV GEMM)
    // Flash fp32 O-partials (512 x 32KB = 16.78MB) live in d_out (dead until
    // the proj GEMM overwrites it).
    char* ws = (char*)d_ws;
    unsigned short* qbf   = (unsigned short*)(ws);
    unsigned short* kbf   = (unsigned short*)(ws + 8388608);
    unsigned short* vtbf  = (unsigned short*)(ws + 16777216);
    unsigned short* WtP   = (unsigned short*)(ws + 25165824);
    unsigned short* WtQKV = (unsigned short*)(ws + 27262976);
    unsigned short* yb    = (unsigned short*)(ws + 33554432);
    unsigned short* qx    = (unsigned short*)(ws + 41943040);
    float* lbase = (float*)(ws + 27262976);             // 512 x 128 floats
    float* parts = out;                                 // 512 x 8192 floats

    prep_kernel<<<6144, 256, 0, stream>>>(
        query, qx, Wq, Wk, Wv, Wp,
        WtQKV, WtQKV + (size_t)C_*C_, WtQKV + 2*(size_t)C_*C_, WtP);

    // Fused QKV GEMM: M=4096, N=3072
    gemm_mfma_kernel<<<dim3(3*C_/128, M_/128), 256, 0, stream>>>(
        qx, WtQKV, bq, bk, bv, qbf, kbf, vtbf, 1);

    flash_mfma_kernel<<<512, 256, 0, stream>>>(qbf, kbf, vtbf, yb, parts, lbase);
    merge_kernel<<<256, 256, 0, stream>>>(parts, lbase, yb);

    // Output projection: M=4096, N=1024 (fp32 out) — overwrites the partials
    gemm_mfma_kernel<<<dim3(C_/128, M_/128), 256, 0, stream>>>(
        yb, WtP, bp, bp, bp, out, nullptr, nullptr, 0);
}